// Round 1
// 1261.325 us; speedup vs baseline: 1.0011x; 1.0011x over previous
//
#include <hip/hip_runtime.h>
#include <hip/hip_bf16.h>

#define N_NODES 50000
#define N_EDGES 640000
#define C_DIM 128
#define B_DIM 64
#define L_DIM 32
#define D_DIM 256
#define S_DIM 128
#define R_DIM 8
#define K_CONV 4
#define NT 16         // nodes per graph block
#define SCAN_BLK 49   // ceil(50000/1024)

typedef unsigned short u16;
typedef __attribute__((ext_vector_type(8))) short bf16x8;   // 8 bf16 = 4 VGPRs
typedef __attribute__((ext_vector_type(4))) float f32x4;

__device__ __forceinline__ float bu2f(u16 u){ return __uint_as_float(((unsigned)u) << 16); }
__device__ __forceinline__ u16 f2bu(float f){
  __hip_bfloat16 h = __float2bfloat16(f);
  return *reinterpret_cast<u16*>(&h);
}
__device__ __forceinline__ float sigmoidf_(float x){ return 1.f/(1.f + expf(-x)); }
__device__ __forceinline__ int clampi(int v, int lo, int hi){ return max(lo, min(v, hi)); }
__device__ __forceinline__ float ldf(const void* p, size_t i, int f){
  return f ? bu2f(((const u16*)p)[i]) : ((const float*)p)[i];
}
__device__ __forceinline__ void stf(void* p, size_t i, int f, float v){
  if (f) ((u16*)p)[i] = f2bu(v); else ((float*)p)[i] = v;
}
__device__ __forceinline__ f32x4 mfma16(bf16x8 a, bf16x8 b, f32x4 c){
  return __builtin_amdgcn_mfma_f32_16x16x32_bf16(a, b, c, 0, 0, 0);
}

// weight arena layout (element offsets); 27 segments in d_in[4..30] order
constexpr int K_SEG = 27;
constexpr int kCum[K_SEG+1] = {
  0, 2048, 3072, 134144, 135168, 184320, 233472, 233856, 234240, 299776,
  300800, 301056, 368640, 370688, 370944, 403712, 403968, 436736, 436864,
  436992, 584448, 584576, 584704, 584832, 601216, 601344, 601472, 601600 };
#define ARENA_TOTAL 601600

struct Ptrs { const void* p[K_SEG]; };

// ---------------- detection (64-lane parallel) ----------------

__global__ void detect_kernel(const unsigned* dp_bits, const unsigned* cand1,
                              const unsigned* cand2, int* flags){
  int lane = threadIdx.x & 63;
  unsigned idx = (unsigned)((lane * 9973u) % (unsigned)N_EDGES);
  int v1 = (cand1[idx] < (unsigned)N_NODES) ? 1 : 0;
  int v2 = (cand2[idx] < (unsigned)N_NODES) ? 1 : 0;
  unsigned long long m1 = __ballot(v1);
  unsigned long long m2 = __ballot(v2);
  if (lane == 0){
    flags[0] = (dp_bits[0] == 0x3F803F80u) ? 1 : 0;
    flags[1] = (__popcll(m1) > __popcll(m2)) ? 1 : 0;   // 1 => d_in[1] is edge_index
  }
}

// ---------------- fused weight-convert ----------------

__global__ __launch_bounds__(256) void cvt_all_kernel(Ptrs ptrs, float* arena,
                                                      const int* flags){
  int i = blockIdx.x*256 + threadIdx.x;
  if (i >= ARENA_TOTAL) return;
  int lo = 0, hi = K_SEG;
  #pragma unroll
  for (int it = 0; it < 5; it++){
    int mid = (lo + hi) >> 1;
    if (i >= kCum[mid]) lo = mid; else hi = mid;
  }
  int elem = i - kCum[lo];
  const void* sp = ptrs.p[lo];
  arena[i] = flags[0] ? bu2f(((const u16*)sp)[elem]) : ((const float*)sp)[elem];
}

// ---------------- weight transpose + bf16 hi/lo split for MFMA ----------------
// WcT[h][j][k] = Wc[h][k][j]; Wm1T[h][j][k] = Wm1[h*128+k][j]; Wm2T[j][k] = Wm2[k][j]

__global__ __launch_bounds__(256) void wtrans_kernel(
    const float* __restrict__ WcF, const float* __restrict__ Wm1F,
    const float* __restrict__ Wm2F,
    u16* __restrict__ WcT_hi, u16* __restrict__ WcT_lo,
    u16* __restrict__ Wm1T_hi, u16* __restrict__ Wm1T_lo,
    u16* __restrict__ Wm2T_hi, u16* __restrict__ Wm2T_lo)
{
  int i = blockIdx.x*256 + threadIdx.x;
  if (i >= 8*C_DIM*C_DIM) return;
  int h = i >> 14, j = (i >> 7) & 127, k = i & 127;
  {
    float w = WcF[(h<<14) + (k<<7) + j];
    u16 hi = f2bu(w); u16 lo = f2bu(w - bu2f(hi));
    WcT_hi[i] = hi; WcT_lo[i] = lo;
  }
  {
    float w = Wm1F[((size_t)((h<<7) + k) << 7) + j];
    u16 hi = f2bu(w); u16 lo = f2bu(w - bu2f(hi));
    Wm1T_hi[i] = hi; Wm1T_lo[i] = lo;
  }
  if (i < C_DIM*C_DIM){
    int j2 = i >> 7, k2 = i & 127;
    float w = Wm2F[(k2<<7) + j2];
    u16 hi = f2bu(w); u16 lo = f2bu(w - bu2f(hi));
    Wm2T_hi[i] = hi; Wm2T_lo[i] = lo;
  }
}

// ---------------- counting sort of edges by dst ----------------

__global__ void hist_kernel(const int* __restrict__ eiA, const int* __restrict__ eiB,
                            const int* __restrict__ flags, int* __restrict__ hist){
  const int* dst = (flags[1] ? eiA : eiB) + N_EDGES;
  int e = blockIdx.x*256 + threadIdx.x;
  if (e >= N_EDGES) return;
  int d = clampi(dst[e], 0, N_NODES-1);
  atomicAdd(&hist[d], 1);
}

__global__ __launch_bounds__(1024) void scan1_kernel(const int* __restrict__ hist,
                                                     int* __restrict__ tmp,
                                                     int* __restrict__ bsums){
  __shared__ int buf[1024];
  int b = blockIdx.x, tid = threadIdx.x;
  int i = b*1024 + tid;
  int v = (i < N_NODES) ? hist[i] : 0;
  buf[tid] = v;
  __syncthreads();
  for (int off = 1; off < 1024; off <<= 1){
    int t = (tid >= off) ? buf[tid-off] : 0;
    __syncthreads();
    buf[tid] += t;
    __syncthreads();
  }
  if (i < N_NODES) tmp[i] = buf[tid];       // inclusive
  if (tid == 1023) bsums[b] = buf[1023];
}

__global__ void scan2_kernel(int* __restrict__ bsums, int* __restrict__ offsets){
  if (threadIdx.x == 0){
    int run = 0;
    for (int b = 0; b < SCAN_BLK; b++){ int v = bsums[b]; bsums[b] = run; run += v; }
    offsets[N_NODES] = run;
  }
}

__global__ __launch_bounds__(1024) void scan3_kernel(int* __restrict__ offsets,
                                                     int* __restrict__ hist,
                                                     const int* __restrict__ bsums){
  int b = blockIdx.x, tid = threadIdx.x;
  int i = b*1024 + tid;
  if (i >= N_NODES) return;
  int incl = offsets[i];
  int h = hist[i];
  int excl = incl - h + bsums[b];
  offsets[i] = excl;
  hist[i] = excl;       // cursor copy for perm_kernel
}

__global__ void perm_kernel(const void* __restrict__ in1, const void* __restrict__ in2,
                            const int* __restrict__ flags, int* __restrict__ cursor,
                            int* __restrict__ sortedSrc, float2* __restrict__ sortedEA){
  int e = blockIdx.x*256 + threadIdx.x;
  if (e >= N_EDGES) return;
  const int f1 = flags[1], f = flags[0];
  const int* ei  = (const int*)(f1 ? in1 : in2);
  const void* eav = f1 ? in2 : in1;
  int d = clampi(ei[N_EDGES + e], 0, N_NODES-1);
  int s = clampi(ei[e], 0, N_NODES-1);
  float a0, a1;
  if (f){ const u16* e16 = (const u16*)eav; a0 = bu2f(e16[2*e]); a1 = bu2f(e16[2*e+1]); }
  else  { const float* e32 = (const float*)eav; a0 = e32[2*e]; a1 = e32[2*e+1]; }
  int pos = atomicAdd(&cursor[d], 1);
  pos = clampi(pos, 0, N_EDGES-1);
  sortedSrc[pos] = s;
  sortedEA[pos] = make_float2(a0, a1);
}

// ---------------- pooling ----------------

__global__ __launch_bounds__(128) void pool_kernel(
    const void* __restrict__ xv, const int* __restrict__ batch,
    float* __restrict__ xsum, int* __restrict__ counts, const int* __restrict__ flags)
{
  int c = threadIdx.x;
  int f = flags[0];
  int n0 = blockIdx.x * 32;
  int nend = min(n0 + 32, N_NODES);
  float acc = 0.f; int cnt = 0;
  int curb = clampi(batch[n0], 0, B_DIM-1);
  for (int n = n0; n < nend; n++){
    int b = clampi(batch[n], 0, B_DIM-1);
    if (b != curb){
      atomicAdd(&xsum[curb*C_DIM + c], acc);
      if (c == 0) atomicAdd(&counts[curb], cnt);
      acc = 0.f; cnt = 0; curb = b;
    }
    acc += ldf(xv, (size_t)n*C_DIM + c, f);
    cnt++;
  }
  atomicAdd(&xsum[curb*C_DIM + c], acc);
  if (c == 0) atomicAdd(&counts[curb], cnt);
}

// ---------------- GRU ----------------

__global__ __launch_bounds__(384) void gru_kernel(
    const float* __restrict__ xsum, const int* __restrict__ counts,
    const float* __restrict__ Wih, const float* __restrict__ bih,
    const float* __restrict__ Whh, const float* __restrict__ bhh,
    float* __restrict__ tokens)
{
  int b = blockIdx.x, j = threadIdx.x;
  __shared__ float xm[C_DIM], h[C_DIM], gh[3*C_DIM], sgi[3*C_DIM];
  __shared__ float mxS;
  if (j == 0){
    int m = 1;
    for (int bb = 0; bb < B_DIM; bb++) m = max(m, counts[bb]);
    mxS = (float)m;
  }
  __syncthreads();
  if (j < C_DIM){ xm[j] = xsum[b*C_DIM + j] / mxS; h[j] = 0.f; }
  __syncthreads();
  float gi = bih[j];
  for (int k = 0; k < C_DIM; k++) gi = fmaf(xm[k], Wih[k*384 + j], gi);
  sgi[j] = gi;
  __syncthreads();
  for (int t = 0; t < L_DIM; t++){
    float acc = bhh[j];
    #pragma unroll 4
    for (int k = 0; k < C_DIM; k++) acc = fmaf(h[k], Whh[k*384 + j], acc);
    gh[j] = acc;
    __syncthreads();
    if (j < C_DIM){
      float r  = sigmoidf_(sgi[j] + gh[j]);
      float z  = sigmoidf_(sgi[C_DIM + j] + gh[C_DIM + j]);
      float nn = tanhf(sgi[2*C_DIM + j] + r*gh[2*C_DIM + j]);
      float hn = (1.f - z)*nn + z*h[j];
      h[j] = hn;
      tokens[((size_t)b*L_DIM + t)*C_DIM + j] = hn;
    }
    __syncthreads();
  }
}

// ---------------- token projection (Win) ----------------

__global__ __launch_bounds__(256) void token_proj_kernel(
    const float* __restrict__ tokens, const float* __restrict__ Win,
    float* __restrict__ x_in, float* __restrict__ z_last)
{
  int row = blockIdx.x;
  int d = threadIdx.x;
  __shared__ float tok[C_DIM];
  if (d < C_DIM) tok[d] = tokens[(size_t)row*C_DIM + d];
  __syncthreads();
  float acc = 0.f;
  for (int k = 0; k < C_DIM; k++) acc = fmaf(tok[k], Win[k*512 + d], acc);
  x_in[(size_t)row*D_DIM + d] = acc;
  if ((row & (L_DIM-1)) == L_DIM-1){
    float acc2 = 0.f;
    for (int k = 0; k < C_DIM; k++) acc2 = fmaf(tok[k], Win[k*512 + D_DIM + d], acc2);
    z_last[(row >> 5)*D_DIM + d] = acc2;
  }
}

// ---------------- xproj ----------------

__global__ __launch_bounds__(256) void xproj_kernel(
    const float* __restrict__ x_in, const float* __restrict__ cw,
    const float* __restrict__ cb, const float* __restrict__ Wx,
    const float* __restrict__ Wdt, const float* __restrict__ bdt,
    float* __restrict__ dt, float* __restrict__ Bp, float* __restrict__ Cp,
    float* __restrict__ x_c)
{
  int row = blockIdx.x; int tid = threadIdx.x;
  int t = row & (L_DIM-1);
  __shared__ float xr[D_DIM];
  __shared__ float dtr[R_DIM];
  float acc0 = cb[tid];
  #pragma unroll
  for (int k = 0; k < K_CONV; k++){
    int tt = t + k - (K_CONV-1);
    if (tt >= 0) acc0 = fmaf(cw[tid*K_CONV + k], x_in[(size_t)(row + tt - t)*D_DIM + tid], acc0);
  }
  float xcv = acc0 * sigmoidf_(acc0);
  x_c[(size_t)row*D_DIM + tid] = xcv;
  xr[tid] = xcv;
  __syncthreads();
  float acc = 0.f;
  #pragma unroll 4
  for (int k = 0; k < D_DIM; k++) acc = fmaf(xr[k], Wx[k*264 + tid], acc);
  if (tid < R_DIM)              dtr[tid] = acc;
  else if (tid < R_DIM+S_DIM)   Bp[(size_t)row*S_DIM + tid - R_DIM] = acc;
  else                          Cp[(size_t)row*S_DIM + tid - (R_DIM+S_DIM)] = acc;
  if (tid < 264 - D_DIM){
    float acc2 = 0.f;
    #pragma unroll 4
    for (int k = 0; k < D_DIM; k++) acc2 = fmaf(xr[k], Wx[k*264 + D_DIM + tid], acc2);
    Cp[(size_t)row*S_DIM + (D_DIM - (R_DIM+S_DIM)) + tid] = acc2;
  }
  __syncthreads();
  float a = bdt[tid];
  #pragma unroll
  for (int r = 0; r < R_DIM; r++) a = fmaf(dtr[r], Wdt[r*D_DIM + tid], a);
  dt[(size_t)row*D_DIM + tid] = (a > 20.f) ? a : log1pf(expf(a));
}

// ---------------- SSM scan ----------------

__global__ __launch_bounds__(256) void ssm_kernel(
    const float* __restrict__ dt, const float* __restrict__ Bp,
    const float* __restrict__ Cp, const float* __restrict__ x_c,
    const float* __restrict__ A_log, const float* __restrict__ Dp_,
    const float* __restrict__ z_last, float* __restrict__ y_last)
{
  int wid = (blockIdx.x*256 + threadIdx.x) >> 6;
  int lane = threadIdx.x & 63;
  int b = wid >> 8, d = wid & (D_DIM-1);
  int s0 = lane*2;
  float A0 = -expf(A_log[d*S_DIM + s0]);
  float A1 = -expf(A_log[d*S_DIM + s0 + 1]);
  float h0 = 0.f, h1 = 0.f;
  for (int t = 0; t < L_DIM; t++){
    int row = b*L_DIM + t;
    float dtv = dt[(size_t)row*D_DIM + d];
    float xv  = x_c[(size_t)row*D_DIM + d];
    float bx = dtv * xv;
    float2 Bv = ((const float2*)(Bp + (size_t)row*S_DIM))[lane];
    h0 = fmaf(expf(dtv*A0), h0, bx*Bv.x);
    h1 = fmaf(expf(dtv*A1), h1, bx*Bv.y);
  }
  int row = b*L_DIM + (L_DIM-1);
  float2 Cv = ((const float2*)(Cp + (size_t)row*S_DIM))[lane];
  float y = h0*Cv.x + h1*Cv.y;
  #pragma unroll
  for (int off = 32; off; off >>= 1) y += __shfl_down(y, off);
  if (lane == 0){
    float xc = x_c[(size_t)row*D_DIM + d];
    float yv = y + Dp_[d]*xc;
    float z  = z_last[b*D_DIM + d];
    yv *= z * sigmoidf_(z);
    y_last[b*D_DIM + d] = yv;
  }
}

// ---------------- proj = ln(y_last @ Wout) @ Wm1[8C:] ----------------

__device__ __forceinline__ float block_sum_128(float v, float* red){
  int c = threadIdx.x;
  red[c] = v; __syncthreads();
  if (c < 64) red[c] += red[c+64];
  __syncthreads();
  if (c < 64){
    float r = red[c];
    #pragma unroll
    for (int off = 32; off; off >>= 1) r += __shfl_down(r, off);
    if (c == 0) red[0] = r;
  }
  __syncthreads();
  float out = red[0];
  __syncthreads();
  return out;
}

__global__ __launch_bounds__(128) void xm_kernel(
    const float* __restrict__ y_last, const float* __restrict__ Wout,
    const float* __restrict__ g_m, const float* __restrict__ b_m,
    const float* __restrict__ Wm1x, float* __restrict__ proj)
{
  int b = blockIdx.x, c = threadIdx.x;
  __shared__ float yr[D_DIM];
  __shared__ float red[C_DIM];
  __shared__ float xmr[C_DIM];
  yr[c]        = y_last[b*D_DIM + c];
  yr[C_DIM+c]  = y_last[b*D_DIM + C_DIM + c];
  __syncthreads();
  float acc = 0.f;
  for (int k = 0; k < D_DIM; k++) acc = fmaf(yr[k], Wout[k*C_DIM + c], acc);
  float mean = block_sum_128(acc, red) * (1.f/C_DIM);
  float dv = acc - mean;
  float var = block_sum_128(dv*dv, red) * (1.f/C_DIM);
  float mo = dv*rsqrtf(var + 1e-5f)*g_m[c] + b_m[c];
  xmr[c] = mo;
  __syncthreads();
  float p = 0.f;
  for (int k = 0; k < C_DIM; k++) p = fmaf(xmr[k], Wm1x[k*C_DIM + c], p);
  proj[b*C_DIM + c] = p;
}

// ---------------- team reduction for 2x128-thread teams in a 256 block ----------------

__device__ __forceinline__ float team_sum256(float v, float* red){
  #pragma unroll
  for (int off = 32; off; off >>= 1) v += __shfl_down(v, off);
  int wv = threadIdx.x >> 6;
  if ((threadIdx.x & 63) == 0) red[wv] = v;
  __syncthreads();
  float s = red[wv & 2] + red[(wv & 2) | 1];
  __syncthreads();
  return s;
}

// ---------------- fused graph path: gather + MFMA matmuls + mlp + LNs ----------------
// 256 threads, NT=16 nodes/block. Matmuls use split-bf16 (hi/lo) 3-term MFMA:
// A*B ~= Ah*Bh + Ah*Bl + Al*Bh  (fp32 accumulate) -> ~17 mantissa bits.
// LDS rows (256B) are XOR-swizzled (byte ^= (row&7)<<4) so ds_read_b128 of a
// column-slice across 16 rows is ~conflict-free (G4).

__global__ __launch_bounds__(256, 2) void graph_kernel(
    const void* __restrict__ xv,
    const int* __restrict__ sortedSrc, const float2* __restrict__ sortedEA,
    const int* __restrict__ offsets,
    const float* __restrict__ WeF, const float* __restrict__ beF,
    const u16* __restrict__ WcT_hi, const u16* __restrict__ WcT_lo,
    const float* __restrict__ bcF,
    const u16* __restrict__ Wm1T_hi, const u16* __restrict__ Wm1T_lo,
    const float* __restrict__ bm1F,
    const float* __restrict__ proj, const int* __restrict__ batch,
    const float* __restrict__ ghF, const float* __restrict__ bhF,
    const u16* __restrict__ Wm2T_hi, const u16* __restrict__ Wm2T_lo,
    const float* __restrict__ bm2F,
    const float* __restrict__ goF, const float* __restrict__ boF,
    const int* __restrict__ flags, void* __restrict__ out)
{
  // LDS: [0,32768) A_hi[8][16][128] bf16 | [32768,65536) A_lo
  //      [65536,69632) Y_hi[16][128]    | [69632,73728) Y_lo
  // pS (16x128 f32) aliases A_hi[0:8192); red aliases A_hi[8192:8224).
  // Aliases are safe: A is dead after the last head's mm1, and pS/red are
  // first written only after the barrier that follows the last mm2.
  __shared__ __align__(16) char smem[73728];
  float* pS  = (float*)smem;
  float* red = (float*)(smem + 8192);

  const int tid = threadIdx.x;
  const int f = flags[0];
  const u16* x16 = (const u16*)xv; const float* x32 = (const float*)xv;
  const int nbase = blockIdx.x * NT;

  // ---- phase 1: edge gather (4 teams of 64 lanes: 2 node-octets x 2 channel halves) ----
  {
    const int lane64 = tid & 63;
    const int team = tid >> 6;
    const int chalf = team & 1;
    const int oct = team >> 1;
    const int c = lane64 + chalf*64;
    float we0[8], we1[8], beh[8];
    #pragma unroll
    for (int h = 0; h < 8; h++){
      we0[h] = WeF[h*2*C_DIM + c];
      we1[h] = WeF[h*2*C_DIM + C_DIM + c];
      beh[h] = beF[h*C_DIM + c];
    }
    for (int g = 0; g < 8; g++){
      int n_l = oct*8 + g;
      int n = nbase + n_l;
      float a[8] = {0,0,0,0,0,0,0,0};
      int q0 = clampi(offsets[n],   0, N_EDGES);
      int q1 = clampi(offsets[n+1], q0, N_EDGES);
      int cnt = q1 - q0;
      float xa = 0.f, xb = 0.f;
      float2 ea0 = make_float2(0.f,0.f), ea1 = make_float2(0.f,0.f);
      if (cnt > 0){
        int s = clampi(sortedSrc[q0], 0, N_NODES-1);
        ea0 = sortedEA[q0];
        xa = f ? bu2f(x16[(size_t)s*C_DIM + c]) : x32[(size_t)s*C_DIM + c];
      }
      if (cnt > 1){
        int s = clampi(sortedSrc[q0+1], 0, N_NODES-1);
        ea1 = sortedEA[q0+1];
        xb = f ? bu2f(x16[(size_t)s*C_DIM + c]) : x32[(size_t)s*C_DIM + c];
      }
      for (int j = 0; j < cnt; j += 2){
        float x0 = xa, x1 = xb;
        float2 e0c = ea0, e1c = ea1;
        int jp = j + 2, jq = j + 3;
        if (jp < cnt){
          int s = clampi(sortedSrc[q0+jp], 0, N_NODES-1);
          ea0 = sortedEA[q0+jp];
          xa = f ? bu2f(x16[(size_t)s*C_DIM + c]) : x32[(size_t)s*C_DIM + c];
        }
        if (jq < cnt){
          int s = clampi(sortedSrc[q0+jq], 0, N_NODES-1);
          ea1 = sortedEA[q0+jq];
          xb = f ? bu2f(x16[(size_t)s*C_DIM + c]) : x32[(size_t)s*C_DIM + c];
        }
        #pragma unroll
        for (int h = 0; h < 8; h++)
          a[h] += fmaxf(fmaf(e0c.x, we0[h], fmaf(e0c.y, we1[h], x0 + beh[h])), 0.f);
        if (j + 1 < cnt){
          #pragma unroll
          for (int h = 0; h < 8; h++)
            a[h] += fmaxf(fmaf(e1c.x, we0[h], fmaf(e1c.y, we1[h], x1 + beh[h])), 0.f);
        }
      }
      int bo = (c*2) ^ ((n_l & 7) << 4);
      #pragma unroll
      for (int h = 0; h < 8; h++){
        u16 hi = f2bu(a[h]);
        u16 lo = f2bu(a[h] - bu2f(hi));
        int rb = (h*16 + n_l)*256 + bo;
        *(u16*)(smem + rb) = hi;
        *(u16*)(smem + 32768 + rb) = lo;
      }
    }
  }
  __syncthreads();

  // ---- phase 2: per-head mm1 (A@Wc,+bc,relu) then mm2 (Y@Wm1_h -> P) via MFMA ----
  const int lane = tid & 63;
  const int wv = tid >> 6;
  const int m16 = lane & 15;       // output row (node) / B col
  const int lg = lane >> 4;        // k-group
  const int colbase = wv * 32;     // this wave's 32 output columns
  const int jA = colbase + m16;

  int aoff[4];
  #pragma unroll
  for (int kk = 0; kk < 4; kk++)
    aoff[kk] = m16*256 + ((kk*64 + lg*16) ^ ((m16 & 7) << 4));

  f32x4 P0 = {0,0,0,0}, P1 = {0,0,0,0};
  for (int h = 0; h < 8; h++){
    f32x4 acc0 = {0,0,0,0}, acc1 = {0,0,0,0};
    #pragma unroll
    for (int kk = 0; kk < 4; kk++){
      bf16x8 ah = *(const bf16x8*)(smem + h*4096 + aoff[kk]);
      bf16x8 al = *(const bf16x8*)(smem + 32768 + h*4096 + aoff[kk]);
      size_t bi0 = ((size_t)(h*C_DIM + jA) << 7) + kk*32 + lg*8;
      bf16x8 bh0 = *(const bf16x8*)(WcT_hi + bi0);
      bf16x8 bl0 = *(const bf16x8*)(WcT_lo + bi0);
      bf16x8 bh1 = *(const bf16x8*)(WcT_hi + bi0 + 2048);
      bf16x8 bl1 = *(const bf16x8*)(WcT_lo + bi0 + 2048);
      acc0 = mfma16(ah, bh0, acc0);
      acc0 = mfma16(ah, bl0, acc0);
      acc0 = mfma16(al, bh0, acc0);
      acc1 = mfma16(ah, bh1, acc1);
      acc1 = mfma16(ah, bl1, acc1);
      acc1 = mfma16(al, bh1, acc1);
    }
    // bias + relu + split-bf16 -> Y lds (C/D layout: row=(lane>>4)*4+r, col=lane&15)
    #pragma unroll
    for (int r = 0; r < 4; r++){
      int row = lg*4 + r;
      int rs = row*256;
      int sw = (row & 7) << 4;
      {
        int col = colbase + m16;
        float v = fmaxf(acc0[r] + bcF[h*C_DIM + col], 0.f);
        u16 hi = f2bu(v); u16 lo = f2bu(v - bu2f(hi));
        int bo = rs + ((col*2) ^ sw);
        *(u16*)(smem + 65536 + bo) = hi;
        *(u16*)(smem + 69632 + bo) = lo;
      }
      {
        int col = colbase + 16 + m16;
        float v = fmaxf(acc1[r] + bcF[h*C_DIM + col], 0.f);
        u16 hi = f2bu(v); u16 lo = f2bu(v - bu2f(hi));
        int bo = rs + ((col*2) ^ sw);
        *(u16*)(smem + 65536 + bo) = hi;
        *(u16*)(smem + 69632 + bo) = lo;
      }
    }
    __syncthreads();
    #pragma unroll
    for (int kk = 0; kk < 4; kk++){
      bf16x8 yh = *(const bf16x8*)(smem + 65536 + aoff[kk]);
      bf16x8 yl = *(const bf16x8*)(smem + 69632 + aoff[kk]);
      size_t bi0 = ((size_t)(h*C_DIM + jA) << 7) + kk*32 + lg*8;
      bf16x8 bh0 = *(const bf16x8*)(Wm1T_hi + bi0);
      bf16x8 bl0 = *(const bf16x8*)(Wm1T_lo + bi0);
      bf16x8 bh1 = *(const bf16x8*)(Wm1T_hi + bi0 + 2048);
      bf16x8 bl1 = *(const bf16x8*)(Wm1T_lo + bi0 + 2048);
      P0 = mfma16(yh, bh0, P0);
      P0 = mfma16(yh, bl0, P0);
      P0 = mfma16(yl, bh0, P0);
      P1 = mfma16(yh, bh1, P1);
      P1 = mfma16(yh, bl1, P1);
      P1 = mfma16(yl, bh1, P1);
    }
    __syncthreads();   // Y reuse next head; also guards pS-vs-A alias after last head
  }
  #pragma unroll
  for (int r = 0; r < 4; r++){
    int row = lg*4 + r;
    pS[row*C_DIM + colbase + m16]      = P0[r];
    pS[row*C_DIM + colbase + 16 + m16] = P1[r];
  }
  __syncthreads();

  // ---- phase 3: mlp1 LN + relu -> h1 (split-bf16 into Y lds) ----
  const int c = tid & 127;
  const int tteam = tid >> 7;
  for (int g = 0; g < 8; g++){
    int n_l = tteam*8 + g;
    int n = nbase + n_l;
    int bi = clampi(batch[n], 0, B_DIM-1);
    float val = pS[n_l*C_DIM + c] + bm1F[c] + proj[bi*C_DIM + c];
    float mean = team_sum256(val, red) * (1.f/C_DIM);
    float dv = val - mean;
    float var = team_sum256(dv*dv, red) * (1.f/C_DIM);
    float v = fmaxf(dv*rsqrtf(var + 1e-5f)*ghF[c] + bhF[c], 0.f);
    u16 hi = f2bu(v); u16 lo = f2bu(v - bu2f(hi));
    int bo = n_l*256 + ((c*2) ^ ((n_l & 7) << 4));
    *(u16*)(smem + 65536 + bo) = hi;
    *(u16*)(smem + 69632 + bo) = lo;
  }
  __syncthreads();

  // ---- phase 4: mlp2 via MFMA ----
  {
    f32x4 A0 = {0,0,0,0}, A1 = {0,0,0,0};
    #pragma unroll
    for (int kk = 0; kk < 4; kk++){
      bf16x8 yh = *(const bf16x8*)(smem + 65536 + aoff[kk]);
      bf16x8 yl = *(const bf16x8*)(smem + 69632 + aoff[kk]);
      size_t bi0 = ((size_t)jA << 7) + kk*32 + lg*8;
      bf16x8 bh0 = *(const bf16x8*)(Wm2T_hi + bi0);
      bf16x8 bl0 = *(const bf16x8*)(Wm2T_lo + bi0);
      bf16x8 bh1 = *(const bf16x8*)(Wm2T_hi + bi0 + 2048);
      bf16x8 bl1 = *(const bf16x8*)(Wm2T_lo + bi0 + 2048);
      A0 = mfma16(yh, bh0, A0);
      A0 = mfma16(yh, bl0, A0);
      A0 = mfma16(yl, bh0, A0);
      A1 = mfma16(yh, bh1, A1);
      A1 = mfma16(yh, bl1, A1);
      A1 = mfma16(yl, bh1, A1);
    }
    #pragma unroll
    for (int r = 0; r < 4; r++){
      int row = lg*4 + r;
      pS[row*C_DIM + colbase + m16]      = A0[r];
      pS[row*C_DIM + colbase + 16 + m16] = A1[r];
    }
  }
  __syncthreads();

  // ---- phase 5: residual + final LN -> out ----
  for (int g = 0; g < 8; g++){
    int n_l = tteam*8 + g;
    int n = nbase + n_l;
    float acc = pS[n_l*C_DIM + c] + bm2F[c]
              + (f ? bu2f(x16[(size_t)n*C_DIM + c]) : x32[(size_t)n*C_DIM + c]);
    float mean = team_sum256(acc, red) * (1.f/C_DIM);
    float dv = acc - mean;
    float var = team_sum256(dv*dv, red) * (1.f/C_DIM);
    float v = dv*rsqrtf(var + 1e-5f)*goF[c] + boF[c];
    stf(out, (size_t)n*C_DIM + c, f, v);
  }
}

// ---------------- launcher ----------------

extern "C" void kernel_launch(void* const* d_in, const int* in_sizes, int n_in,
                              void* d_out, int out_size, void* d_ws, size_t ws_size,
                              hipStream_t stream)
{
  const void* x      = d_in[0];
  const void* in1    = d_in[1];
  const void* in2    = d_in[2];
  const int*  batch  = (const int*)d_in[3];
  (void)in_sizes; (void)n_in; (void)out_size; (void)ws_size;

  char* ws = (char*)d_ws;
  size_t off = 0;
  auto alloc = [&](size_t nbytes)->char*{
    char* p = ws + off;
    off += (nbytes + 255) & ~(size_t)255;
    return p;
  };
  int*   flags = (int*)alloc(8);
  float* arena = (float*)alloc((size_t)ARENA_TOTAL*4);
  int* hist    = (int*)alloc((size_t)N_NODES*4);          // becomes cursor after scan
  int* offsets = (int*)alloc((size_t)(N_NODES+1)*4);
  int* bsums   = (int*)alloc((size_t)SCAN_BLK*4);
  int* sortedSrc = (int*)alloc((size_t)N_EDGES*4);
  float2* sortedEA = (float2*)alloc((size_t)N_EDGES*8);
  float* proj   = (float*)alloc((size_t)B_DIM*C_DIM*4);
  float* xsum   = (float*)alloc((size_t)B_DIM*C_DIM*4);
  int*   counts = (int*)alloc((size_t)B_DIM*4);
  float* tokens = (float*)alloc((size_t)B_DIM*L_DIM*C_DIM*4);  // reused as Bp
  float* x_in   = (float*)alloc((size_t)B_DIM*L_DIM*D_DIM*4);  // reused as dtb
  float* x_c    = (float*)alloc((size_t)B_DIM*L_DIM*D_DIM*4);
  float* Cp     = (float*)alloc((size_t)B_DIM*L_DIM*S_DIM*4);
  float* z_last = (float*)alloc((size_t)B_DIM*D_DIM*4);
  float* y_last = (float*)alloc((size_t)B_DIM*D_DIM*4);
  u16* WcT_hi  = (u16*)alloc((size_t)8*C_DIM*C_DIM*2);
  u16* WcT_lo  = (u16*)alloc((size_t)8*C_DIM*C_DIM*2);
  u16* Wm1T_hi = (u16*)alloc((size_t)8*C_DIM*C_DIM*2);
  u16* Wm1T_lo = (u16*)alloc((size_t)8*C_DIM*C_DIM*2);
  u16* Wm2T_hi = (u16*)alloc((size_t)C_DIM*C_DIM*2);
  u16* Wm2T_lo = (u16*)alloc((size_t)C_DIM*C_DIM*2);
  float* Bp  = tokens;
  float* dtb = x_in;

  // weight arena views (match kCum)
  float* WeF   = arena + 0;      float* beF   = arena + 2048;
  float* WcF   = arena + 3072;   float* bcF   = arena + 134144;
  float* WihF  = arena + 135168; float* WhhF  = arena + 184320;
  float* bihF  = arena + 233472; float* bhhF  = arena + 233856;
  float* WinF  = arena + 234240; float* cwF   = arena + 299776;
  float* cbF   = arena + 300800; float* WxF   = arena + 301056;
  float* WdtF  = arena + 368640; float* bdtF  = arena + 370688;
  float* AlF   = arena + 370944; float* DpF   = arena + 403712;
  float* WoutF = arena + 403968; float* gmF   = arena + 436736;
  float* bmF   = arena + 436864; float* Wm1F  = arena + 436992;
  float* bm1F  = arena + 584448; float* ghF   = arena + 584576;
  float* bhF   = arena + 584704; float* Wm2F  = arena + 584832;
  float* bm2F  = arena + 601216; float* goF   = arena + 601344;
  float* boF   = arena + 601472;

  // 0) detect dtype + edge-input order
  detect_kernel<<<1, 64, 0, stream>>>((const unsigned*)d_in[19],
                                      (const unsigned*)in1, (const unsigned*)in2, flags);

  // 1) all weight converts in one launch, then MFMA transpose/split
  Ptrs ptrs;
  for (int i = 0; i < K_SEG; i++) ptrs.p[i] = d_in[4 + i];
  cvt_all_kernel<<<(ARENA_TOTAL + 255)/256, 256, 0, stream>>>(ptrs, arena, flags);
  wtrans_kernel<<<(8*C_DIM*C_DIM + 255)/256, 256, 0, stream>>>(
      WcF, Wm1F, Wm2F, WcT_hi, WcT_lo, Wm1T_hi, Wm1T_lo, Wm2T_hi, Wm2T_lo);

  // 2) counting sort of edges by dst (3-phase parallel scan + pre-gather)
  hipMemsetAsync(hist, 0, (size_t)N_NODES*4, stream);
  hist_kernel<<<(N_EDGES + 255)/256, 256, 0, stream>>>((const int*)in1, (const int*)in2, flags, hist);
  scan1_kernel<<<SCAN_BLK, 1024, 0, stream>>>(hist, offsets, bsums);
  scan2_kernel<<<1, 64, 0, stream>>>(bsums, offsets);
  scan3_kernel<<<SCAN_BLK, 1024, 0, stream>>>(offsets, hist, bsums);
  perm_kernel<<<(N_EDGES + 255)/256, 256, 0, stream>>>(in1, in2, flags, hist, sortedSrc, sortedEA);

  // 3) sequential path
  hipMemsetAsync(xsum, 0, (size_t)B_DIM*C_DIM*4 + 256, stream);  // xsum + counts
  pool_kernel<<<(N_NODES + 31)/32, 128, 0, stream>>>(x, batch, xsum, counts, flags);
  gru_kernel<<<B_DIM, 384, 0, stream>>>(xsum, counts, WihF, bihF, WhhF, bhhF, tokens);
  token_proj_kernel<<<B_DIM*L_DIM, 256, 0, stream>>>(tokens, WinF, x_in, z_last);
  xproj_kernel<<<B_DIM*L_DIM, 256, 0, stream>>>(x_in, cwF, cbF, WxF, WdtF, bdtF, dtb, Bp, Cp, x_c);
  ssm_kernel<<<(B_DIM*D_DIM)/4, 256, 0, stream>>>(dtb, Bp, Cp, x_c, AlF, DpF, z_last, y_last);
  xm_kernel<<<B_DIM, 128, 0, stream>>>(y_last, WoutF, gmF, bmF, Wm1F + 8*C_DIM*C_DIM, proj);

  // 4) fused graph path (MFMA) + mlp1 + mlp2 + final LN -> d_out
  graph_kernel<<<N_NODES/NT, 256, 0, stream>>>(
      x, sortedSrc, sortedEA, offsets, WeF, beF,
      WcT_hi, WcT_lo, bcF, Wm1T_hi, Wm1T_lo, bm1F,
      proj, batch, ghF, bhF, Wm2T_hi, Wm2T_lo, bm2F, goF, boF, flags, d_out);
}